// Round 1
// baseline (690.659 us; speedup 1.0000x reference)
//
#include <hip/hip_runtime.h>
#include <math.h>

#define HDIM 2048
#define OUTN 32000
#define KOUT 3072

__device__ __forceinline__ float wave_reduce_sum(float v) {
    #pragma unroll
    for (int off = 32; off > 0; off >>= 1)
        v += __shfl_down(v, off, 64);
    return v;
}

__device__ __forceinline__ float sigmoidf(float x) {
    return 1.0f / (1.0f + __expf(-x));
}

// One LSTM layer for batch=1. Grid: 2048 blocks x 256 threads.
// Block n: wave w computes gate row (n + w*2048): w0=i, w1=f, w2=g, w3=o.
// Input x (length 2048) is passed as two 1024-element halves (xa, xb) so the
// concat(category, input) case and the contiguous-h1 case use the same kernel.
__global__ __launch_bounds__(256) void lstm_kernel(
    const float* __restrict__ xa,    // x[0:1024]
    const float* __restrict__ xb,    // x[1024:2048]
    const float* __restrict__ h,     // [2048]
    const float* __restrict__ c,     // [2048]
    const float* __restrict__ w_ih,  // [8192, 2048] row-major
    const float* __restrict__ w_hh,  // [8192, 2048]
    const float* __restrict__ b_ih,  // [8192]
    const float* __restrict__ b_hh,  // [8192]
    float* __restrict__ h_out,       // [2048]
    float* __restrict__ c_out)       // [2048]
{
    const int wave = threadIdx.x >> 6;
    const int lane = threadIdx.x & 63;
    const int n    = blockIdx.x;          // hidden index
    const int row  = n + wave * HDIM;     // gate row

    const float4* wih4 = (const float4*)(w_ih + (size_t)row * HDIM);
    const float4* whh4 = (const float4*)(w_hh + (size_t)row * HDIM);
    const float4* xa4  = (const float4*)xa;   // 256 float4
    const float4* xb4  = (const float4*)xb;   // 256 float4
    const float4* h4   = (const float4*)h;    // 512 float4

    float acc = 0.f;
    #pragma unroll
    for (int it = 0; it < 8; ++it) {
        const int k4 = it * 64 + lane;                  // float4 index in row
        float4 w1 = wih4[k4];
        float4 w2 = whh4[k4];
        float4 xv = (it < 4) ? xa4[k4] : xb4[k4 - 256]; // wave-uniform select
        float4 hv = h4[k4];
        acc += w1.x * xv.x + w1.y * xv.y + w1.z * xv.z + w1.w * xv.w;
        acc += w2.x * hv.x + w2.y * hv.y + w2.z * hv.z + w2.w * hv.w;
    }
    acc = wave_reduce_sum(acc);

    __shared__ float sg[4];
    if (lane == 0) sg[wave] = acc + b_ih[row] + b_hh[row];
    __syncthreads();

    if (threadIdx.x == 0) {
        float gi = sigmoidf(sg[0]);
        float gf = sigmoidf(sg[1]);
        float gg = tanhf(sg[2]);
        float go = sigmoidf(sg[3]);
        float cn = gf * c[n] + gi * gg;
        float hn = go * tanhf(cn);
        c_out[n] = cn;
        h_out[n] = hn;
    }
}

// logits[row] = dot(w_out[row,:], concat(category, h2)) + b_out[row]
// Grid: 8000 blocks x 256 threads (4 rows/block, one per wave).
__global__ __launch_bounds__(256) void logits_kernel(
    const float* __restrict__ cat,    // [1024]
    const float* __restrict__ h2,     // [2048]
    const float* __restrict__ w_out,  // [32000, 3072]
    const float* __restrict__ b_out,  // [32000]
    float* __restrict__ logits)       // [32000]
{
    const int wave = threadIdx.x >> 6;
    const int lane = threadIdx.x & 63;
    const int row  = blockIdx.x * 4 + wave;

    const float4* w4 = (const float4*)(w_out + (size_t)row * KOUT);
    const float4* c4 = (const float4*)cat;  // 256 float4
    const float4* h4 = (const float4*)h2;   // 512 float4

    float acc = 0.f;
    #pragma unroll
    for (int it = 0; it < 12; ++it) {
        const int k4 = it * 64 + lane;
        float4 w = w4[k4];
        float4 v = (it < 4) ? c4[k4] : h4[k4 - 256];
        acc += w.x * v.x + w.y * v.y + w.z * v.z + w.w * v.w;
    }
    acc = wave_reduce_sum(acc);
    if (lane == 0) logits[row] = acc + b_out[row];
}

// Single-block online logsumexp over 32000 logits -> *logz = max + log(sum exp)
__global__ __launch_bounds__(1024) void lse_kernel(
    const float* __restrict__ logits, float* __restrict__ logz)
{
    float m = -INFINITY, s = 0.f;
    for (int i = threadIdx.x; i < OUTN; i += 1024) {  // every thread gets >=31 elems
        float v = logits[i];
        if (v > m) { s = s * __expf(m - v) + 1.f; m = v; }
        else       { s += __expf(v - m); }
    }
    #pragma unroll
    for (int off = 32; off > 0; off >>= 1) {
        float m2 = __shfl_down(m, off, 64);
        float s2 = __shfl_down(s, off, 64);
        float mn = fmaxf(m, m2);
        s = s * __expf(m - mn) + s2 * __expf(m2 - mn);
        m = mn;
    }
    __shared__ float sm[16], ss[16];
    const int wave = threadIdx.x >> 6;
    const int lane = threadIdx.x & 63;
    if (lane == 0) { sm[wave] = m; ss[wave] = s; }
    __syncthreads();
    if (threadIdx.x == 0) {
        float M = sm[0], S = ss[0];
        for (int w = 1; w < 16; ++w) {
            float mn = fmaxf(M, sm[w]);
            S = S * __expf(M - mn) + ss[w] * __expf(sm[w] - mn);
            M = mn;
        }
        *logz = M + logf(S);
    }
}

// logp[i] = logits[i] - logZ.  Grid: 125 x 256 == 32000 exactly.
__global__ __launch_bounds__(256) void sub_kernel(
    const float* __restrict__ logits, const float* __restrict__ logz,
    float* __restrict__ out)
{
    const int i = blockIdx.x * 256 + threadIdx.x;
    out[i] = logits[i] - *logz;
}

extern "C" void kernel_launch(void* const* d_in, const int* in_sizes, int n_in,
                              void* d_out, int out_size, void* d_ws, size_t ws_size,
                              hipStream_t stream) {
    const float* category = (const float*)d_in[0];   // [1024]
    const float* input    = (const float*)d_in[1];   // [1024]
    const float* hidden   = (const float*)d_in[2];   // [2,1,2048]
    const float* cell     = (const float*)d_in[3];   // [2,1,2048]
    const float* w_ih_l0  = (const float*)d_in[4];
    const float* w_hh_l0  = (const float*)d_in[5];
    const float* b_ih_l0  = (const float*)d_in[6];
    const float* b_hh_l0  = (const float*)d_in[7];
    const float* w_ih_l1  = (const float*)d_in[8];
    const float* w_hh_l1  = (const float*)d_in[9];
    const float* b_ih_l1  = (const float*)d_in[10];
    const float* b_hh_l1  = (const float*)d_in[11];
    const float* w_out    = (const float*)d_in[12];
    const float* b_out    = (const float*)d_in[13];

    float* out  = (float*)d_out;
    float* logp = out;                    // [32000]
    float* h1   = out + OUTN;             // new_hidden[0]
    float* h2   = out + OUTN + HDIM;      // new_hidden[1]
    float* c1   = out + OUTN + 2 * HDIM;  // new_cell[0]
    float* c2   = out + OUTN + 3 * HDIM;  // new_cell[1]

    float* logits = (float*)d_ws;         // [32000]
    float* logz   = logits + OUTN;        // [1]

    // layer 0: x = concat(category, input)
    lstm_kernel<<<HDIM, 256, 0, stream>>>(category, input,
                                          hidden, cell,
                                          w_ih_l0, w_hh_l0, b_ih_l0, b_hh_l0,
                                          h1, c1);
    // layer 1: x = h1 (contiguous; split into two halves for the shared kernel)
    lstm_kernel<<<HDIM, 256, 0, stream>>>(h1, h1 + 1024,
                                          hidden + HDIM, cell + HDIM,
                                          w_ih_l1, w_hh_l1, b_ih_l1, b_hh_l1,
                                          h2, c2);
    logits_kernel<<<OUTN / 4, 256, 0, stream>>>(category, h2, w_out, b_out, logits);
    lse_kernel<<<1, 1024, 0, stream>>>(logits, logz);
    sub_kernel<<<OUTN / 256, 256, 0, stream>>>(logits, logz, logp);
}